// Round 1
// baseline (597.530 us; speedup 1.0000x reference)
//
#include <hip/hip_runtime.h>
#include <stdint.h>

// Hamming distance via one-hot nibble packing + popcount.
// xq, xp: [8192][512] int32 tokens in [0,4).
// Packed: each row -> 64 uint32 (one-hot nibble per token).
// dist[n][m] = 512 - sum_w popc(qpk[n][w] & ppk[m][w]).

#define NROWS   8192
#define DTOK    512
#define DWORDS  64          // 512 tokens * 4 bits / 32
#define BTILE   128         // block output tile: 128x128
#define NTHREADS 256        // 16x16 threads, 8x8 outputs each

__global__ __launch_bounds__(NTHREADS) void pack_kernel(
    const int* __restrict__ xq, const int* __restrict__ xp,
    uint32_t* __restrict__ qpk, uint32_t* __restrict__ ppk, int nwords) {
  int idx = blockIdx.x * NTHREADS + threadIdx.x;   // packed word index
  if (idx >= nwords) return;
  const int4* q = ((const int4*)xq) + (size_t)idx * 2;
  int4 a = q[0], b = q[1];
  uint32_t v = (1u << a.x) | (1u << (4 + a.y)) | (1u << (8 + a.z)) | (1u << (12 + a.w))
             | (1u << (16 + b.x)) | (1u << (20 + b.y)) | (1u << (24 + b.z)) | (1u << (28 + b.w));
  qpk[idx] = v;
  const int4* p = ((const int4*)xp) + (size_t)idx * 2;
  a = p[0]; b = p[1];
  v = (1u << a.x) | (1u << (4 + a.y)) | (1u << (8 + a.z)) | (1u << (12 + a.w))
    | (1u << (16 + b.x)) | (1u << (20 + b.y)) | (1u << (24 + b.z)) | (1u << (28 + b.w));
  ppk[idx] = v;
}

__global__ __launch_bounds__(NTHREADS, 2) void hamming_kernel(
    const uint32_t* __restrict__ qpk, const uint32_t* __restrict__ ppk,
    int* __restrict__ out) {
  // LDS: 128 rows x 64 dwords each side, XOR-swizzled in 16B chunks:
  // phys dword = row*64 + ((chunk ^ (row>>3)) << 2).  This spreads rows that
  // differ by 8 (the per-thread stride) across distinct bank groups.
  __shared__ uint32_t qs[BTILE * DWORDS];
  __shared__ uint32_t ps[BTILE * DWORDS];

  const int t  = threadIdx.x;
  const int br = blockIdx.y;   // q-tile index
  const int bc = blockIdx.x;   // p-tile index

  // ---- stage: 128 rows * 16 chunks (uint4) per side ----
  const uint4* qg = (const uint4*)(qpk + (size_t)br * BTILE * DWORDS);
  const uint4* pg = (const uint4*)(ppk + (size_t)bc * BTILE * DWORDS);
  #pragma unroll
  for (int idx = t; idx < BTILE * 16; idx += NTHREADS) {
    int row = idx >> 4, ch = idx & 15;
    int phys = row * DWORDS + ((ch ^ (row >> 3)) << 2);
    *(uint4*)(qs + phys) = qg[idx];
    *(uint4*)(ps + phys) = pg[idx];
  }
  __syncthreads();

  const int tr = t >> 4;   // 0..15: which 8-row band of q
  const int tc = t & 15;   // 0..15: which 8-row band of p

  int acc[8][8];
  #pragma unroll
  for (int i = 0; i < 8; ++i)
    #pragma unroll
    for (int j = 0; j < 8; ++j) acc[i][j] = 0;

  // ---- main loop: 16 chunks of 16B per row ----
  for (int c = 0; c < 16; ++c) {
    uint4 qa[8], pb[8];
    #pragma unroll
    for (int i = 0; i < 8; ++i) {
      int row = tr * 8 + i;                   // row>>3 == tr
      qa[i] = *(const uint4*)(qs + row * DWORDS + (((c ^ tr) & 15) << 2));
    }
    #pragma unroll
    for (int j = 0; j < 8; ++j) {
      int row = tc * 8 + j;                   // row>>3 == tc
      pb[j] = *(const uint4*)(ps + row * DWORDS + (((c ^ tc) & 15) << 2));
    }
    #pragma unroll
    for (int i = 0; i < 8; ++i)
      #pragma unroll
      for (int j = 0; j < 8; ++j) {
        acc[i][j] += __popc(qa[i].x & pb[j].x) + __popc(qa[i].y & pb[j].y)
                   + __popc(qa[i].z & pb[j].z) + __popc(qa[i].w & pb[j].w);
      }
  }

  // ---- store: dist = 512 - matches, 2 x int4 per output row ----
  const int row0 = br * BTILE + tr * 8;
  const int col0 = bc * BTILE + tc * 8;
  #pragma unroll
  for (int i = 0; i < 8; ++i) {
    int4 v0, v1;
    v0.x = DTOK - acc[i][0]; v0.y = DTOK - acc[i][1];
    v0.z = DTOK - acc[i][2]; v0.w = DTOK - acc[i][3];
    v1.x = DTOK - acc[i][4]; v1.y = DTOK - acc[i][5];
    v1.z = DTOK - acc[i][6]; v1.w = DTOK - acc[i][7];
    int4* dst = (int4*)(out + (size_t)(row0 + i) * NROWS + col0);
    dst[0] = v0;
    dst[1] = v1;
  }
}

extern "C" void kernel_launch(void* const* d_in, const int* in_sizes, int n_in,
                              void* d_out, int out_size, void* d_ws, size_t ws_size,
                              hipStream_t stream) {
  const int* xq = (const int*)d_in[0];
  const int* xp = (const int*)d_in[1];
  int* out = (int*)d_out;

  const int nwords = NROWS * DWORDS;          // 524288 words per array
  uint32_t* qpk = (uint32_t*)d_ws;            // 2 MB
  uint32_t* ppk = qpk + nwords;               // 2 MB

  pack_kernel<<<(nwords + NTHREADS - 1) / NTHREADS, NTHREADS, 0, stream>>>(
      xq, xp, qpk, ppk, nwords);

  dim3 grid(NROWS / BTILE, NROWS / BTILE);    // 64 x 64
  hamming_kernel<<<grid, NTHREADS, 0, stream>>>(qpk, ppk, out);
}

// Round 3
// 386.600 us; speedup vs baseline: 1.5456x; 1.5456x over previous
//
#include <hip/hip_runtime.h>
#include <stdint.h>

// Hamming distance as an i8 MFMA GEMM.
// Encoding: token t in [0,4) -> 3 i8 features (s1, s0, s1*s0), s=+-1.
// dot[n,m] = sum_{k<1536} q_k p_k = 4*matches - 512  =>  dist = 512 - ((dot+512)>>2).
// Exact in i32.

#define NROWS  8192
#define NTOK   512
#define KB     1536          // K in bytes (3 features * 512 tokens)
#define BM     128           // block tile (output 128x128)
#define BK     64            // K-step in bytes
#define KSTEPS (KB / BK)     // 24
#define NTHREADS 256         // 4 waves; each wave owns a 64x64 quadrant

typedef int v4i __attribute__((ext_vector_type(4)));

// ---------------- pack: tokens -> +-1 i8 features, feature-blocked layout ----
// Q[row][c*512 + d] (bytes), c in {0,1,2}: c0 = s1, c1 = s0, c2 = s1*s0.
__global__ __launch_bounds__(256) void pack_kernel(
    const int* __restrict__ xq, const int* __restrict__ xp,
    uint32_t* __restrict__ qpk, uint32_t* __restrict__ ppk) {
  int idx = blockIdx.x * 256 + threadIdx.x;        // 8192*128 quads
  int row = idx >> 7, q = idx & 127;               // 4 tokens per thread

  const int4 a = ((const int4*)xq)[(size_t)row * 128 + q];
  const int4 b = ((const int4*)xp)[(size_t)row * 128 + q];
  int ta[4] = {a.x, a.y, a.z, a.w};
  int tb[4] = {b.x, b.y, b.z, b.w};

  uint32_t qa0 = 0, qa1 = 0, qa2 = 0, pb0 = 0, pb1 = 0, pb2 = 0;
  #pragma unroll
  for (int j = 0; j < 4; ++j) {
    int b1 = (ta[j] >> 1) & 1, b0 = ta[j] & 1;
    qa0 |= ((uint32_t)(uint8_t)(1 - 2 * b1)) << (8 * j);
    qa1 |= ((uint32_t)(uint8_t)(1 - 2 * b0)) << (8 * j);
    qa2 |= ((uint32_t)(uint8_t)(1 - 2 * (b1 ^ b0))) << (8 * j);
    b1 = (tb[j] >> 1) & 1; b0 = tb[j] & 1;
    pb0 |= ((uint32_t)(uint8_t)(1 - 2 * b1)) << (8 * j);
    pb1 |= ((uint32_t)(uint8_t)(1 - 2 * b0)) << (8 * j);
    pb2 |= ((uint32_t)(uint8_t)(1 - 2 * (b1 ^ b0))) << (8 * j);
  }
  size_t base = (size_t)row * 384 + q;             // dword index, KB/4 = 384
  qpk[base]       = qa0;  ppk[base]       = pb0;
  qpk[base + 128] = qa1;  ppk[base + 128] = pb1;
  qpk[base + 256] = qa2;  ppk[base + 256] = pb2;
}

// ---------------- main GEMM -------------------------------------------------
// LDS tiles [128 rows][64 bytes], seg-swizzled: 16B segment seg of row r lives
// at phys seg' = seg ^ ((r>>1)&3).  global_load_lds writes linearly (lane*16),
// so the *global source* is inverse-swizzled per lane (rule 21) and ds_read
// applies the same XOR.  This keeps ds_read_b128 at <=2-way conflict (free).
__global__ __launch_bounds__(NTHREADS) void hamming_mfma(
    const uint8_t* __restrict__ Q, const uint8_t* __restrict__ P,
    int* __restrict__ out) {
  __shared__ __align__(1024) uint8_t As[BM * BK];   // 8 KB
  __shared__ __align__(1024) uint8_t Bs[BM * BK];   // 8 KB

  const int t = threadIdx.x;
  const int l = t & 63;
  const int w = t >> 6;
  const int wr = w >> 1, wc = w & 1;      // wave's 64x64 quadrant
  const int br = blockIdx.y, bc = blockIdx.x;

  const uint8_t* qbase = Q + (size_t)br * BM * KB;
  const uint8_t* pbase = P + (size_t)bc * BM * KB;

  // staging geometry: chunk s = w*2+i covers LDS bytes [s*1024, s*1024+1024);
  // lane l's 16B goes to LDS linear (row = s*16 + l/4, segp = l&3), so it must
  // come from global seg = segp ^ f(row).  f(row) = (row>>1)&3; row%16 = l/4
  // and s*16 is 0 mod 16, so f = (l>>3)&3.
  const int srow0 = w * 32 + (l >> 2);    // row of chunk i=0 (i=1: +16)
  const int sseg  = ((l & 3) ^ ((l >> 3) & 3)) * 16;

  v4i acc[4][4] = {};

  for (int kk = 0; kk < KSTEPS; ++kk) {
    const int kb = kk * BK;
    // ---- stage 16 KB via 4x global_load_lds(16B) per thread ----
    #pragma unroll
    for (int i = 0; i < 2; ++i) {
      const int s = w * 2 + i;
      const int row = srow0 + i * 16;
      const uint8_t* ga = qbase + (size_t)row * KB + kb + sseg;
      const uint8_t* gb = pbase + (size_t)row * KB + kb + sseg;
      __builtin_amdgcn_global_load_lds(
          (const __attribute__((address_space(1))) void*)ga,
          (__attribute__((address_space(3))) void*)(As + s * 1024), 16, 0, 0);
      __builtin_amdgcn_global_load_lds(
          (const __attribute__((address_space(1))) void*)gb,
          (__attribute__((address_space(3))) void*)(Bs + s * 1024), 16, 0, 0);
    }
    __syncthreads();

    // ---- fragments: A row = quadrant row, 16 contiguous i8 at k-block l>>4
    v4i af[4], bf[4];
    #pragma unroll
    for (int m = 0; m < 4; ++m) {
      const int row = wr * 64 + m * 16 + (l & 15);
      const int seg = ((l >> 4) ^ ((row >> 1) & 3)) * 16;
      af[m] = *(const v4i*)(As + row * BK + seg);
    }
    #pragma unroll
    for (int n = 0; n < 4; ++n) {
      const int row = wc * 64 + n * 16 + (l & 15);
      const int seg = ((l >> 4) ^ ((row >> 1) & 3)) * 16;
      bf[n] = *(const v4i*)(Bs + row * BK + seg);
    }

    #pragma unroll
    for (int m = 0; m < 4; ++m)
      #pragma unroll
      for (int n = 0; n < 4; ++n)
        acc[m][n] = __builtin_amdgcn_mfma_i32_16x16x64_i8(af[m], bf[n], acc[m][n], 0, 0, 0);

    __syncthreads();
  }

  // ---- epilogue: dist = 512 - ((dot+512)>>2); C/D: col=l&15, row=(l>>4)*4+r
  const int row0 = br * BM + wr * 64 + (l >> 4) * 4;
  const int col0 = bc * BM + wc * 64 + (l & 15);
  #pragma unroll
  for (int m = 0; m < 4; ++m)
    #pragma unroll
    for (int n = 0; n < 4; ++n) {
      const size_t rbase = (size_t)(row0 + m * 16) * NROWS + (col0 + n * 16);
      #pragma unroll
      for (int r = 0; r < 4; ++r)
        out[rbase + (size_t)r * NROWS] = NTOK - ((acc[m][n][r] + 512) >> 2);
    }
}

extern "C" void kernel_launch(void* const* d_in, const int* in_sizes, int n_in,
                              void* d_out, int out_size, void* d_ws, size_t ws_size,
                              hipStream_t stream) {
  const int* xq = (const int*)d_in[0];
  const int* xp = (const int*)d_in[1];
  int* out = (int*)d_out;

  uint32_t* qpk = (uint32_t*)d_ws;                      // 8192*1536 B = 12 MB
  uint32_t* ppk = qpk + (size_t)NROWS * KB / 4;         // 12 MB

  pack_kernel<<<(NROWS * 128) / 256, 256, 0, stream>>>(xq, xp, qpk, ppk);

  dim3 grid(NROWS / BM, NROWS / BM);                    // 64 x 64
  hamming_mfma<<<grid, NTHREADS, 0, stream>>>((const uint8_t*)qpk,
                                              (const uint8_t*)ppk, out);
}